// Round 8
// baseline (214.642 us; speedup 1.0000x reference)
//
#include <hip/hip_runtime.h>

#define N 4096
#define D 512
#define C 64
#define MARGIN 1.0f
#define TILE 128
#define ROWB 128       // LDS row bytes per chunk (BK=64 bf16); xor-swizzle, no pad
#define NTILES (N / TILE)                 // 32
#define NTRI (NTILES * (NTILES + 1) / 2)  // 528 triangular tiles (work-stealing cursor)
#define FINF 3.0e38f
#define SLOTW 16
#define PCAP 1024      // per-tile LDS pair-record capacity (mean 244, +48 sigma)
#define GRID 512       // <= resident capacity at (256,3): spin barrier deadlock-safe

// ctrl slots: [0]=pair cursor, [1]=tile cursor, [2]=barrier1, [3]=barrier2, [4]=done
typedef __attribute__((ext_vector_type(8))) short short8;
typedef __attribute__((ext_vector_type(4))) float floatx4;

__device__ __forceinline__ unsigned short f2bf(float f) {
  unsigned int u = __float_as_uint(f);
  u += 0x7FFFu + ((u >> 16) & 1u);  // RNE
  return (unsigned short)(u >> 16);
}

__device__ __forceinline__ void gload_lds16(const void* g, void* l) {
  __builtin_amdgcn_global_load_lds(
      (const __attribute__((address_space(1))) unsigned int*)g,
      (__attribute__((address_space(3))) unsigned int*)l, 16, 0, 0);
}

// device-scope grid barrier: release-fence, arrive, agent-scope spin, acquire-fence.
// Safe: GRID=512 blocks always co-resident (capacity 768 at 3/CU, any packing).
__device__ __forceinline__ void grid_barrier(unsigned int* cnt, unsigned int total) {
  __syncthreads();
  if (threadIdx.x == 0) {
    __threadfence();  // release (buffer_wbl2: flush dirty L2 for cross-XCD visibility)
    atomicAdd(cnt, 1u);
    while (__hip_atomic_load(cnt, __ATOMIC_RELAXED, __HIP_MEMORY_SCOPE_AGENT) < total)
      __builtin_amdgcn_s_sleep(2);
    __threadfence();  // acquire (buffer_inv)
  }
  __syncthreads();
}

__global__ __launch_bounds__(256, 3) void fused_kernel(
    const float* __restrict__ E, const int* __restrict__ targets,
    unsigned short* __restrict__ Ebf, float* __restrict__ norms,
    unsigned int* __restrict__ an_sq_bits, float* __restrict__ accs,
    unsigned int* __restrict__ ctrl, uint2* __restrict__ pairs,
    float* __restrict__ out) {
  const int tid = threadIdx.x;
  const int wave = tid >> 6, lane = tid & 63;
  const int quad = lane >> 4, l16 = lane & 15;

  // ---------------- Phase 1: prep (bf16 convert + norms + an_sq init) -----------
  // wave-local: each wave handles 2 rows, lane covers floats [lane*8, lane*8+8)
  if (blockIdx.x < 8) {  // an_sq init: 8 blocks x 512 entries
    an_sq_bits[blockIdx.x * 512 + tid] = 0x7F800000u;
    an_sq_bits[blockIdx.x * 512 + 256 + tid] = 0x7F800000u;
  }
#pragma unroll
  for (int rr = 0; rr < 2; rr++) {
    const int row = blockIdx.x * 8 + wave * 2 + rr;
    const float4 v0 = reinterpret_cast<const float4*>(E + (size_t)row * D)[lane * 2];
    const float4 v1 = reinterpret_cast<const float4*>(E + (size_t)row * D)[lane * 2 + 1];
    float s = v0.x * v0.x + v0.y * v0.y + v0.z * v0.z + v0.w * v0.w +
              v1.x * v1.x + v1.y * v1.y + v1.z * v1.z + v1.w * v1.w;
    uint4 p;
    p.x = ((unsigned int)f2bf(v0.y) << 16) | f2bf(v0.x);
    p.y = ((unsigned int)f2bf(v0.w) << 16) | f2bf(v0.z);
    p.z = ((unsigned int)f2bf(v1.y) << 16) | f2bf(v1.x);
    p.w = ((unsigned int)f2bf(v1.w) << 16) | f2bf(v1.z);
    reinterpret_cast<uint4*>(Ebf + (size_t)row * D)[lane] = p;
#pragma unroll
    for (int off = 32; off > 0; off >>= 1) s += __shfl_down(s, off);
    if (lane == 0) norms[row] = s;
  }

  grid_barrier(&ctrl[2], GRID);

  // ---------------- Phase 2: gemm + masked-min + pair emission ------------------
  __shared__ alignas(16) unsigned char As[TILE * ROWB];  // 16 KB
  __shared__ alignas(16) unsigned char Bs[TILE * ROWB];  // 16 KB
  __shared__ float s_rmin[2][TILE];
  __shared__ float s_cmin[2][TILE];
  __shared__ unsigned int s_pkey[PCAP];  // 4 KB
  __shared__ float s_psq[PCAP];          // 4 KB
  __shared__ unsigned int s_pcnt, s_pbase, s_tile;

  const int wr = wave >> 1, wc = wave & 1;
  const int lr = lane >> 3;
  const int lq = (lane & 7) ^ lr;
  const int lofs = lr * (D * 2) + lq * 16;
  const int swz = l16 & 7;
  int rA[4], rB[4], cq[2];
#pragma unroll
  for (int s = 0; s < 4; s++) {
    rA[s] = (wr * 64 + s * 16 + l16) * ROWB;
    rB[s] = (wc * 64 + s * 16 + l16) * ROWB;
  }
#pragma unroll
  for (int ks = 0; ks < 2; ks++) cq[ks] = ((ks * 4 + quad) ^ swz) * 16;

  for (;;) {
    if (tid == 0) s_tile = atomicAdd(&ctrl[1], 1u);
    __syncthreads();
    const unsigned int u = s_tile;
    if (u >= NTRI) break;
    if (tid == 0) s_pcnt = 0u;
    int i = (int)((sqrtf(8.0f * (float)u + 1.0f) - 1.0f) * 0.5f);
    while ((i + 1) * (i + 2) / 2 <= (int)u) ++i;
    while (i * (i + 1) / 2 > (int)u) --i;
    const int tm = (int)u - i * (i + 1) / 2;
    const int tn = i;
    const int rowBase = tm * TILE, colBase = tn * TILE;
    const unsigned char* gA = (const unsigned char*)Ebf + (size_t)rowBase * (D * 2);
    const unsigned char* gB = (const unsigned char*)Ebf + (size_t)colBase * (D * 2);

    floatx4 acc[4][4];
#pragma unroll
    for (int a = 0; a < 4; a++)
#pragma unroll
      for (int b = 0; b < 4; b++) acc[a][b] = (floatx4){0.f, 0.f, 0.f, 0.f};

    for (int k0b = 0; k0b < D * 2; k0b += 128) {  // 8 chunks of 64 k-elems
#pragma unroll
      for (int t = 0; t < 4; t++) {
        const int g = wave * 4 + t;
        gload_lds16(gA + (size_t)g * 8 * (D * 2) + lofs + k0b, As + g * 1024);
        gload_lds16(gB + (size_t)g * 8 * (D * 2) + lofs + k0b, Bs + g * 1024);
      }
      __syncthreads();  // drains DMA (vmcnt) before reads
#pragma unroll
      for (int ks = 0; ks < 2; ks++) {
        short8 af[4], bf[4];
#pragma unroll
        for (int s = 0; s < 4; s++) {
          af[s] = *reinterpret_cast<const short8*>(As + rA[s] + cq[ks]);
          bf[s] = *reinterpret_cast<const short8*>(Bs + rB[s] + cq[ks]);
        }
#pragma unroll
        for (int sm = 0; sm < 4; sm++)
#pragma unroll
          for (int sn = 0; sn < 4; sn++)
            acc[sm][sn] = __builtin_amdgcn_mfma_f32_16x16x32_bf16(af[sm], bf[sn], acc[sm][sn], 0, 0, 0);
      }
      __syncthreads();
    }

    // Epilogue. C/D layout: col = lane&15, row = quad*4 + reg (m89/m91).
    int tcol[4], gcolv[4];
    float ncol[4];
#pragma unroll
    for (int sn = 0; sn < 4; sn++) {
      const int gc = colBase + wc * 64 + sn * 16 + l16;
      gcolv[sn] = gc;
      tcol[sn] = targets[gc];
      ncol[sn] = norms[gc];
    }
    float colmin[4] = {FINF, FINF, FINF, FINF};
#pragma unroll
    for (int sm = 0; sm < 4; sm++) {
#pragma unroll
      for (int r = 0; r < 4; r++) {
        const int rloc = wr * 64 + sm * 16 + quad * 4 + r;
        const int grow = rowBase + rloc;
        const int trow = targets[grow];
        const float nrow = norms[grow];
        float rowmin = FINF;
#pragma unroll
        for (int sn = 0; sn < 4; sn++) {
          const float sq = fmaxf(nrow + ncol[sn] - 2.0f * acc[sm][sn][r], 0.0f);
          if (tcol[sn] != trow) {
            rowmin = fminf(rowmin, sq);
            colmin[sn] = fminf(colmin[sn], sq);
          } else if (grow < gcolv[sn]) {  // same-class pair (i<j): emit record
            const unsigned int idx = atomicAdd(&s_pcnt, 1u);
            if (idx < PCAP) {
              s_pkey[idx] = ((unsigned int)grow << 12) | (unsigned int)gcolv[sn];
              s_psq[idx] = sq;
            } else {  // overflow fallback (astronomically rare)
              const unsigned int g = atomicAdd(&ctrl[0], 1u);
              pairs[g] = make_uint2(((unsigned int)grow << 12) | (unsigned int)gcolv[sn],
                                    __float_as_uint(sq));
            }
          }
        }
#pragma unroll
        for (int off = 1; off < 16; off <<= 1) rowmin = fminf(rowmin, __shfl_xor(rowmin, off));
        if (l16 == 0) s_rmin[wc][rloc] = rowmin;
      }
    }
#pragma unroll
    for (int sn = 0; sn < 4; sn++) {
      float cm = colmin[sn];
      cm = fminf(cm, __shfl_xor(cm, 16));
      cm = fminf(cm, __shfl_xor(cm, 32));
      if (quad == 0) s_cmin[wr][wc * 64 + sn * 16 + l16] = cm;
    }
    __syncthreads();
    if (tid < TILE) {
      const float m = fminf(s_rmin[0][tid], s_rmin[1][tid]);
      if (m < FINF) atomicMin(&an_sq_bits[rowBase + tid], __float_as_uint(m));
    } else {
      const int c = tid - TILE;
      const float m = fminf(s_cmin[0][c], s_cmin[1][c]);
      if (m < FINF) atomicMin(&an_sq_bits[colBase + c], __float_as_uint(m));
    }
    const unsigned int npair = min(s_pcnt, (unsigned int)PCAP);
    if (tid == 0) s_pbase = atomicAdd(&ctrl[0], npair);
    __syncthreads();
    for (unsigned int r = tid; r < npair; r += 256)
      pairs[s_pbase + r] = make_uint2(s_pkey[r], __float_as_uint(s_psq[r]));
    __syncthreads();  // s_pkey/s_psq/s_tile safe to reuse
  }

  grid_barrier(&ctrl[3], GRID);

  // ---------------- Phase 3: flat loss pass over pair records -------------------
  __shared__ float s_sum[4];
  __shared__ unsigned int s_cnt[4], s_cor[4];
  __shared__ int s_last;
  const unsigned int M = atomicAdd(&ctrl[0], 0u);  // coherent read of pair count
  float bsum = 0.f;
  unsigned int bcnt = 0, bcor = 0;
  for (unsigned int r = blockIdx.x * 256 + tid; r < M; r += GRID * 256) {
    const uint2 rec = pairs[r];
    const int a = (int)(rec.x >> 12);  // anchor (smaller original index)
    const float sq = __uint_as_float(rec.y);
    const float an = __uint_as_float(an_sq_bits[a]);
    if (sqrtf(sq) - sqrtf(an) + MARGIN > 0.0f) {
      bcnt++;
      bsum += fmaxf(sq - an + MARGIN, 0.0f);
      if (sq < an) bcor++;
    }
  }
#pragma unroll
  for (int off = 32; off > 0; off >>= 1) {
    bsum += __shfl_down(bsum, off);
    bcnt += __shfl_down(bcnt, off);
    bcor += __shfl_down(bcor, off);
  }
  if (lane == 0) { s_sum[wave] = bsum; s_cnt[wave] = bcnt; s_cor[wave] = bcor; }
  __syncthreads();
  if (tid == 0) {
    float* slot = accs + (size_t)(blockIdx.x & (C - 1)) * SLOTW;
    atomicAdd(&slot[0], s_sum[0] + s_sum[1] + s_sum[2] + s_sum[3]);
    atomicAdd((unsigned int*)&slot[1], s_cnt[0] + s_cnt[1] + s_cnt[2] + s_cnt[3]);
    atomicAdd((unsigned int*)&slot[2], s_cor[0] + s_cor[1] + s_cor[2] + s_cor[3]);
    __threadfence();  // release
    s_last = (atomicAdd(&ctrl[4], 1u) == (unsigned int)GRID - 1u);
  }
  __syncthreads();
  if (s_last) {
    __threadfence();  // acquire
    if (tid < C) {
      float sum = __uint_as_float(atomicAdd((unsigned int*)&accs[(size_t)tid * SLOTW + 0], 0u));
      unsigned int cnt = atomicAdd((unsigned int*)&accs[(size_t)tid * SLOTW + 1], 0u);
      unsigned int cor = atomicAdd((unsigned int*)&accs[(size_t)tid * SLOTW + 2], 0u);
#pragma unroll
      for (int off = 32; off > 0; off >>= 1) {
        sum += __shfl_down(sum, off);
        cnt += __shfl_down(cnt, off);
        cor += __shfl_down(cor, off);
      }
      if (tid == 0) {
        const float denom = (float)(cnt > 0u ? cnt : 1u);
        out[0] = sum / denom;
        out[1] = (float)cor / denom;
      }
    }
  }
}

extern "C" void kernel_launch(void* const* d_in, const int* in_sizes, int n_in,
                              void* d_out, int out_size, void* d_ws, size_t ws_size,
                              hipStream_t stream) {
  const float* E = (const float*)d_in[0];
  const int* targets = (const int*)d_in[1];
  float* out = (float*)d_out;
  char* ws = (char*)d_ws;
  size_t off = 0;
  unsigned short* Ebf = (unsigned short*)(ws + off); off += (size_t)N * D * 2;  // 4 MB
  float* norms = (float*)(ws + off); off += (size_t)N * 4;                      // 16 KB
  unsigned int* an_sq = (unsigned int*)(ws + off); off += (size_t)N * 4;        // 16 KB
  float* accs = (float*)(ws + off); off += (size_t)C * SLOTW * 4;               // 4 KB
  unsigned int* ctrl = (unsigned int*)(ws + off); off += 256;                   // cursors/barriers
  uint2* pairs = (uint2*)(ws + off);                                            // pair records

  // zero accs + ctrl in one capture-legal memset node (accs and ctrl are contiguous)
  hipMemsetAsync(accs, 0, (size_t)C * SLOTW * 4 + 256, stream);
  fused_kernel<<<dim3(GRID), dim3(256), 0, stream>>>(E, targets, Ebf, norms, an_sq, accs,
                                                     ctrl, pairs, out);
}

// Round 9
// 99.842 us; speedup vs baseline: 2.1498x; 2.1498x over previous
//
#include <hip/hip_runtime.h>

#define N 4096
#define D 512
#define C 64
#define MARGIN 1.0f
#define TILE 128
#define NTILES (N / TILE)                 // 32
#define NTRI (NTILES * (NTILES + 1) / 2)  // 528 triangular blocks
#define FINF 3.0e38f
#define SLOTW 16
#define PCAP 1024      // per-block LDS pair-record capacity (mean 244, +48 sigma)
#define LOSSB 128      // loss_kernel blocks
#define PANELB 16384   // panel bytes: 16 rows x 1 KB (512 bf16)

typedef __attribute__((ext_vector_type(8))) short short8;
typedef __attribute__((ext_vector_type(4))) float floatx4;

__device__ __forceinline__ unsigned short f2bf(float f) {
  unsigned int u = __float_as_uint(f);
  u += 0x7FFFu + ((u >> 16) & 1u);  // RNE
  return (unsigned short)(u >> 16);
}

// K1: fp32 -> bf16 PANEL format + exact fp32 norms + an_sq init. One block per panel
// (16 rows). Panel layout: addr = panel*16K + q16*256 + row*16  (q16 = 16B k-chunk).
// A wave's MFMA fragment load then = 1 KB contiguous global_load_dwordx4.
__global__ __launch_bounds__(256) void prep_kernel(const float* __restrict__ E,
                                                   unsigned short* __restrict__ panels,
                                                   float* __restrict__ norms,
                                                   unsigned int* __restrict__ an_sq_bits) {
  const int b = blockIdx.x;  // panel index, 256 total
  const int tid = threadIdx.x;
  const int row = tid & 15, qg = tid >> 4;  // thread covers chunks q = qg*4+j
  if (tid < 16) an_sq_bits[b * 16 + tid] = 0x7F800000u;  // +inf
  const float4* Er = reinterpret_cast<const float4*>(E + (size_t)(b * 16 + row) * D);
  uint4* P4 = reinterpret_cast<uint4*>(panels + (size_t)b * (PANELB / 2));
  float s = 0.f;
#pragma unroll
  for (int j = 0; j < 4; j++) {
    const int q = qg * 4 + j;
    const float4 v0 = Er[q * 2];
    const float4 v1 = Er[q * 2 + 1];
    s += v0.x * v0.x + v0.y * v0.y + v0.z * v0.z + v0.w * v0.w +
         v1.x * v1.x + v1.y * v1.y + v1.z * v1.z + v1.w * v1.w;
    uint4 p;
    p.x = ((unsigned int)f2bf(v0.y) << 16) | f2bf(v0.x);
    p.y = ((unsigned int)f2bf(v0.w) << 16) | f2bf(v0.z);
    p.z = ((unsigned int)f2bf(v1.y) << 16) | f2bf(v1.x);
    p.w = ((unsigned int)f2bf(v1.w) << 16) | f2bf(v1.z);
    P4[q * 16 + row] = p;  // coalesced: 16 consecutive rows = 256 B contiguous
  }
  // row-norm: 4 lanes per row within the wave (qg bits are lane bits [5:4])
  s += __shfl_xor(s, 16);
  s += __shfl_xor(s, 32);
  __shared__ float s_n[4][16];
  const int wave = tid >> 6, lane = tid & 63;
  if (lane < 16) s_n[wave][lane] = s;
  __syncthreads();
  if (tid < 16) norms[b * 16 + tid] = s_n[0][tid] + s_n[1][tid] + s_n[2][tid] + s_n[3][tid];
}

// K2: E*E^T via bf16 MFMA with REGISTER-DIRECT panel loads — no LDS staging, no
// K-loop barriers. Each frag = 1 KB coalesced dwordx4; register double-buffer lets
// the compiler interleave loads with MFMA using partial vmcnt waits (AITER-style).
// Fused epilogue: masked min -> atomicMin(an_sq); same-class pair emission.
__global__ __launch_bounds__(256, 2) void gemm_min_kernel(const unsigned short* __restrict__ panels,
                                                          const float* __restrict__ norms,
                                                          const int* __restrict__ targets,
                                                          unsigned int* __restrict__ an_sq_bits,
                                                          uint2* __restrict__ pairs,
                                                          unsigned int* __restrict__ ctrl) {
  const int u = blockIdx.x;
  int i = (int)((sqrtf(8.0f * (float)u + 1.0f) - 1.0f) * 0.5f);
  while ((i + 1) * (i + 2) / 2 <= u) ++i;
  while (i * (i + 1) / 2 > u) --i;
  const int tm = u - i * (i + 1) / 2;
  const int tn = i;

  __shared__ float s_rmin[2][TILE];
  __shared__ float s_cmin[2][TILE];
  __shared__ unsigned int s_pkey[PCAP];  // 4 KB
  __shared__ float s_psq[PCAP];          // 4 KB
  __shared__ unsigned int s_pcnt, s_pbase;

  const int tid = threadIdx.x;
  const int wave = tid >> 6, lane = tid & 63;
  const int quad = lane >> 4, l16 = lane & 15;
  const int wr = wave >> 1, wc = wave & 1;  // wave owns rows [wr*64,+64) x cols [wc*64,+64)
  const int rowBase = tm * TILE, colBase = tn * TILE;
  if (tid == 0) s_pcnt = 0u;

  // wave's A panels: tm*8 + wr*4 + s ; B panels: tn*8 + wc*4 + s (s = frag 0..3)
  const unsigned char* pA = (const unsigned char*)panels + (size_t)(tm * 8 + wr * 4) * PANELB;
  const unsigned char* pB = (const unsigned char*)panels + (size_t)(tn * 8 + wc * 4) * PANELB;
  const int lofs = quad * 256 + l16 * 16;  // lane's 16B within a 1 KB k-step slab

  floatx4 acc[4][4];
#pragma unroll
  for (int a = 0; a < 4; a++)
#pragma unroll
    for (int b = 0; b < 4; b++) acc[a][b] = (floatx4){0.f, 0.f, 0.f, 0.f};

  short8 af[2][4], bf[2][4];
#pragma unroll
  for (int s = 0; s < 4; s++) {
    af[0][s] = *reinterpret_cast<const short8*>(pA + s * PANELB + lofs);
    bf[0][s] = *reinterpret_cast<const short8*>(pB + s * PANELB + lofs);
  }
#pragma unroll 2
  for (int ks = 0; ks < 16; ks++) {  // 16 k-steps of 32 (K=512), no barriers
    const int cur = ks & 1, nxt = cur ^ 1;
    if (ks < 15) {
      const int off = (ks + 1) * 1024 + lofs;
#pragma unroll
      for (int s = 0; s < 4; s++) {
        af[nxt][s] = *reinterpret_cast<const short8*>(pA + s * PANELB + off);
        bf[nxt][s] = *reinterpret_cast<const short8*>(pB + s * PANELB + off);
      }
    }
#pragma unroll
    for (int sm = 0; sm < 4; sm++)
#pragma unroll
      for (int sn = 0; sn < 4; sn++)
        acc[sm][sn] = __builtin_amdgcn_mfma_f32_16x16x32_bf16(af[cur][sm], bf[cur][sn], acc[sm][sn], 0, 0, 0);
  }

  // Epilogue. C/D layout: col = lane&15, row = quad*4 + reg (m89/m91).
  int tcol[4], gcolv[4];
  float ncol[4];
#pragma unroll
  for (int sn = 0; sn < 4; sn++) {
    const int gc = colBase + wc * 64 + sn * 16 + l16;
    gcolv[sn] = gc;
    tcol[sn] = targets[gc];
    ncol[sn] = norms[gc];
  }
  float colmin[4] = {FINF, FINF, FINF, FINF};
#pragma unroll
  for (int sm = 0; sm < 4; sm++) {
#pragma unroll
    for (int r = 0; r < 4; r++) {
      const int rloc = wr * 64 + sm * 16 + quad * 4 + r;
      const int grow = rowBase + rloc;
      const int trow = targets[grow];
      const float nrow = norms[grow];
      float rowmin = FINF;
#pragma unroll
      for (int sn = 0; sn < 4; sn++) {
        const float sq = fmaxf(nrow + ncol[sn] - 2.0f * acc[sm][sn][r], 0.0f);
        if (tcol[sn] != trow) {
          rowmin = fminf(rowmin, sq);
          colmin[sn] = fminf(colmin[sn], sq);
        } else if (grow < gcolv[sn]) {  // same-class pair (i<j): emit record
          const unsigned int idx = atomicAdd(&s_pcnt, 1u);
          if (idx < PCAP) {
            s_pkey[idx] = ((unsigned int)grow << 12) | (unsigned int)gcolv[sn];
            s_psq[idx] = sq;
          } else {  // overflow fallback (astronomically rare)
            const unsigned int g = atomicAdd(&ctrl[0], 1u);
            pairs[g] = make_uint2(((unsigned int)grow << 12) | (unsigned int)gcolv[sn],
                                  __float_as_uint(sq));
          }
        }
      }
#pragma unroll
      for (int off = 1; off < 16; off <<= 1) rowmin = fminf(rowmin, __shfl_xor(rowmin, off));
      if (l16 == 0) s_rmin[wc][rloc] = rowmin;
    }
  }
#pragma unroll
  for (int sn = 0; sn < 4; sn++) {
    float cm = colmin[sn];
    cm = fminf(cm, __shfl_xor(cm, 16));
    cm = fminf(cm, __shfl_xor(cm, 32));
    if (quad == 0) s_cmin[wr][wc * 64 + sn * 16 + l16] = cm;
  }
  __syncthreads();
  if (tid < TILE) {
    const float m = fminf(s_rmin[0][tid], s_rmin[1][tid]);
    if (m < FINF) atomicMin(&an_sq_bits[rowBase + tid], __float_as_uint(m));
  } else {
    const int c = tid - TILE;
    const float m = fminf(s_cmin[0][c], s_cmin[1][c]);
    if (m < FINF) atomicMin(&an_sq_bits[colBase + c], __float_as_uint(m));
  }
  // flush the compacted pair list: ONE global cursor-add per block, coalesced copy
  const unsigned int npair = min(s_pcnt, (unsigned int)PCAP);
  if (tid == 0) s_pbase = atomicAdd(&ctrl[0], npair);
  __syncthreads();
  for (unsigned int r = tid; r < npair; r += 256)
    pairs[s_pbase + r] = make_uint2(s_pkey[r], __float_as_uint(s_psq[r]));
}

// K3: flat pass over emitted pair records + fused last-block finalize.
__global__ __launch_bounds__(256) void loss_kernel(const uint2* __restrict__ pairs,
                                                   const unsigned int* __restrict__ an_sq_bits,
                                                   float* __restrict__ accs,
                                                   unsigned int* __restrict__ ctrl,
                                                   float* __restrict__ out) {
  const int tid = threadIdx.x, wave = tid >> 6, lane = tid & 63;
  const unsigned int M = ctrl[0];
  __shared__ float s_sum[4];
  __shared__ unsigned int s_cnt[4], s_cor[4];
  __shared__ int s_last;
  float bsum = 0.f;
  unsigned int bcnt = 0, bcor = 0;
  for (unsigned int r = blockIdx.x * 256 + tid; r < M; r += LOSSB * 256) {
    const uint2 rec = pairs[r];
    const int a = (int)(rec.x >> 12);  // anchor (smaller original index)
    const float sq = __uint_as_float(rec.y);
    const float an = __uint_as_float(an_sq_bits[a]);
    if (sqrtf(sq) - sqrtf(an) + MARGIN > 0.0f) {
      bcnt++;
      bsum += fmaxf(sq - an + MARGIN, 0.0f);
      if (sq < an) bcor++;
    }
  }
#pragma unroll
  for (int off = 32; off > 0; off >>= 1) {
    bsum += __shfl_down(bsum, off);
    bcnt += __shfl_down(bcnt, off);
    bcor += __shfl_down(bcor, off);
  }
  if (lane == 0) { s_sum[wave] = bsum; s_cnt[wave] = bcnt; s_cor[wave] = bcor; }
  __syncthreads();
  if (tid == 0) {
    float* slot = accs + (size_t)(blockIdx.x & (C - 1)) * SLOTW;
    atomicAdd(&slot[0], s_sum[0] + s_sum[1] + s_sum[2] + s_sum[3]);
    atomicAdd((unsigned int*)&slot[1], s_cnt[0] + s_cnt[1] + s_cnt[2] + s_cnt[3]);
    atomicAdd((unsigned int*)&slot[2], s_cor[0] + s_cor[1] + s_cor[2] + s_cor[3]);
    __threadfence();  // release
    s_last = (atomicAdd(&ctrl[1], 1u) == (unsigned int)LOSSB - 1u);
  }
  __syncthreads();
  if (s_last) {  // last block: reduce the 64 slots, finalize the two scalars
    __threadfence();  // acquire
    if (tid < C) {
      float sum = __uint_as_float(atomicAdd((unsigned int*)&accs[(size_t)tid * SLOTW + 0], 0u));
      unsigned int cnt = atomicAdd((unsigned int*)&accs[(size_t)tid * SLOTW + 1], 0u);
      unsigned int cor = atomicAdd((unsigned int*)&accs[(size_t)tid * SLOTW + 2], 0u);
#pragma unroll
      for (int off = 32; off > 0; off >>= 1) {
        sum += __shfl_down(sum, off);
        cnt += __shfl_down(cnt, off);
        cor += __shfl_down(cor, off);
      }
      if (tid == 0) {
        const float denom = (float)(cnt > 0u ? cnt : 1u);
        out[0] = sum / denom;
        out[1] = (float)cor / denom;
      }
    }
  }
}

extern "C" void kernel_launch(void* const* d_in, const int* in_sizes, int n_in,
                              void* d_out, int out_size, void* d_ws, size_t ws_size,
                              hipStream_t stream) {
  const float* E = (const float*)d_in[0];
  const int* targets = (const int*)d_in[1];
  float* out = (float*)d_out;
  char* ws = (char*)d_ws;
  size_t off = 0;
  unsigned short* panels = (unsigned short*)(ws + off); off += (size_t)N * D * 2;  // 4 MB
  float* norms = (float*)(ws + off); off += (size_t)N * 4;                         // 16 KB
  unsigned int* an_sq = (unsigned int*)(ws + off); off += (size_t)N * 4;           // 16 KB
  float* accs = (float*)(ws + off); off += (size_t)C * SLOTW * 4;                  // 4 KB
  unsigned int* ctrl = (unsigned int*)(ws + off); off += 256;                      // cursor+done
  uint2* pairs = (uint2*)(ws + off);                                               // pair records

  // zero accs + ctrl in one capture-legal memset node (contiguous)
  hipMemsetAsync(accs, 0, (size_t)C * SLOTW * 4 + 256, stream);
  prep_kernel<<<dim3(N / 16), dim3(256), 0, stream>>>(E, panels, norms, an_sq);
  gemm_min_kernel<<<dim3(NTRI), dim3(256), 0, stream>>>(panels, norms, targets, an_sq, pairs, ctrl);
  loss_kernel<<<dim3(LOSSB), dim3(256), 0, stream>>>(pairs, an_sq, accs, ctrl, out);
}

// Round 10
// 98.187 us; speedup vs baseline: 2.1861x; 1.0169x over previous
//
#include <hip/hip_runtime.h>

#define N 4096
#define D 512
#define C 64
#define MARGIN 1.0f
#define TROW 64        // tile rows
#define TCOL 128       // tile cols
#define NBLK 1056      // triangular-cover tiles: sum_b (2b+2), b<32 -> 4.1 blocks/CU
#define FINF 3.0e38f
#define SLOTW 16
#define PCAP 512       // per-block LDS pair-record capacity (mean 122, +13 sigma)
#define LOSSB 128

typedef __attribute__((ext_vector_type(8))) short short8;
typedef __attribute__((ext_vector_type(4))) float floatx4;

__device__ __forceinline__ unsigned short f2bf(float f) {
  unsigned int u = __float_as_uint(f);
  u += 0x7FFFu + ((u >> 16) & 1u);  // RNE
  return (unsigned short)(u >> 16);
}

// async global->LDS DMA, 16 B/lane; dest = wave-uniform base + lane*16 (m97/m104)
__device__ __forceinline__ void gload_lds16(const void* g, void* l) {
  __builtin_amdgcn_global_load_lds(
      (const __attribute__((address_space(1))) unsigned int*)g,
      (__attribute__((address_space(3))) unsigned int*)l, 16, 0, 0);
}

// K1: fp32 -> bf16 (row-major) + exact fp32 norms + an_sq init. 256 blocks x 16 rows.
// Block 0 also zeros accs+ctrl (adjacent in ws) -> no separate memset node.
__global__ __launch_bounds__(256) void prep_kernel(const float* __restrict__ E,
                                                   unsigned short* __restrict__ Ebf,
                                                   float* __restrict__ norms,
                                                   unsigned int* __restrict__ an_sq_bits,
                                                   unsigned int* __restrict__ accs_u) {
  const int b = blockIdx.x;
  const int tid = threadIdx.x, wave = tid >> 6, lane = tid & 63;
  if (tid < 16) an_sq_bits[b * 16 + tid] = 0x7F800000u;  // +inf
  if (b == 0)
    for (int k = tid; k < C * SLOTW + 64; k += 256) accs_u[k] = 0u;  // accs + ctrl
#pragma unroll
  for (int rr = 0; rr < 4; rr++) {
    const int row = b * 16 + wave * 4 + rr;
    const float4* Er = reinterpret_cast<const float4*>(E + (size_t)row * D);
    const float4 v0 = Er[lane * 2];
    const float4 v1 = Er[lane * 2 + 1];
    float s = v0.x * v0.x + v0.y * v0.y + v0.z * v0.z + v0.w * v0.w +
              v1.x * v1.x + v1.y * v1.y + v1.z * v1.z + v1.w * v1.w;
    uint4 p;
    p.x = ((unsigned int)f2bf(v0.y) << 16) | f2bf(v0.x);
    p.y = ((unsigned int)f2bf(v0.w) << 16) | f2bf(v0.z);
    p.z = ((unsigned int)f2bf(v1.y) << 16) | f2bf(v1.x);
    p.w = ((unsigned int)f2bf(v1.w) << 16) | f2bf(v1.z);
    reinterpret_cast<uint4*>(Ebf + (size_t)row * D)[lane] = p;  // coalesced 1 KB/wave
#pragma unroll
    for (int off = 32; off > 0; off >>= 1) s += __shfl_down(s, off);
    if (lane == 0) norms[row] = s;
  }
}

// K2: E*E^T via bf16 MFMA, 64x128 tiles (1056 blocks, ~4 co-resident/CU so barrier
// stalls of one block are hidden by another's work — fixes the 2.06-blocks/CU
// starvation that kept MfmaUtil at ~6%). DMA staging + xor swizzle (proven R5/R7).
// Fused: masked-min -> atomicMin(an_sq); same-class pair emission (i<j only).
__global__ __launch_bounds__(256, 4) void gemm_min_kernel(const unsigned short* __restrict__ Ebf,
                                                          const float* __restrict__ norms,
                                                          const int* __restrict__ targets,
                                                          unsigned int* __restrict__ an_sq_bits,
                                                          uint2* __restrict__ pairs,
                                                          unsigned int* __restrict__ ctrl) {
  // decode u = b*b + b + a, a in [0, 2b+2): tile rows [64a,+64), cols [128b,+128)
  const int u = blockIdx.x;
  int b = (int)((sqrtf(4.0f * (float)u + 1.0f) - 1.0f) * 0.5f);
  while ((b + 1) * (b + 2) <= u) ++b;
  while (b * (b + 1) > u) --b;
  const int a = u - b * (b + 1);
  const int rowBase = a * TROW, colBase = b * TCOL;

  __shared__ alignas(16) unsigned char As[TROW * 128];  // 8 KB
  __shared__ alignas(16) unsigned char Bs[TCOL * 128];  // 16 KB
  __shared__ float s_rmin[2][TROW];
  __shared__ float s_cmin[2][TCOL];
  __shared__ unsigned int s_pkey[PCAP];  // 2 KB
  __shared__ float s_psq[PCAP];          // 2 KB
  __shared__ unsigned int s_pcnt, s_pbase;

  const int tid = threadIdx.x;
  const int wave = tid >> 6, lane = tid & 63;
  const int quad = lane >> 4, l16 = lane & 15;
  const int wr = wave >> 1, wc = wave & 1;  // wave: rows [wr*32,+32) x cols [wc*64,+64)
  if (tid == 0) s_pcnt = 0u;

  const int lr = lane >> 3;
  const int lq = (lane & 7) ^ lr;  // phys chunk = logical ^ (row&7)
  const int lofs = lr * (D * 2) + lq * 16;
  const unsigned char* gA = (const unsigned char*)Ebf + (size_t)rowBase * (D * 2);
  const unsigned char* gB = (const unsigned char*)Ebf + (size_t)colBase * (D * 2);

  const int swz = l16 & 7;
  int rA[2], rB[4], cq[2];
#pragma unroll
  for (int s = 0; s < 2; s++) rA[s] = (wr * 32 + s * 16 + l16) * 128;
#pragma unroll
  for (int s = 0; s < 4; s++) rB[s] = (wc * 64 + s * 16 + l16) * 128;
#pragma unroll
  for (int ks = 0; ks < 2; ks++) cq[ks] = ((ks * 4 + quad) ^ swz) * 16;

  floatx4 acc[2][4];
#pragma unroll
  for (int x = 0; x < 2; x++)
#pragma unroll
    for (int y = 0; y < 4; y++) acc[x][y] = (floatx4){0.f, 0.f, 0.f, 0.f};

  for (int k0b = 0; k0b < D * 2; k0b += 128) {  // 8 chunks of 64 k-elems
#pragma unroll
    for (int t = 0; t < 2; t++) {  // A: 8 8-row groups, 2 per wave
      const int g = wave * 2 + t;
      gload_lds16(gA + (size_t)g * 8 * (D * 2) + lofs + k0b, As + g * 1024);
    }
#pragma unroll
    for (int t = 0; t < 4; t++) {  // B: 16 8-row groups, 4 per wave
      const int g = wave * 4 + t;
      gload_lds16(gB + (size_t)g * 8 * (D * 2) + lofs + k0b, Bs + g * 1024);
    }
    __syncthreads();  // drains DMA before reads
#pragma unroll
    for (int ks = 0; ks < 2; ks++) {
      short8 af[2], bf[4];
#pragma unroll
      for (int s = 0; s < 2; s++) af[s] = *reinterpret_cast<const short8*>(As + rA[s] + cq[ks]);
#pragma unroll
      for (int s = 0; s < 4; s++) bf[s] = *reinterpret_cast<const short8*>(Bs + rB[s] + cq[ks]);
#pragma unroll
      for (int sm = 0; sm < 2; sm++)
#pragma unroll
        for (int sn = 0; sn < 4; sn++)
          acc[sm][sn] = __builtin_amdgcn_mfma_f32_16x16x32_bf16(af[sm], bf[sn], acc[sm][sn], 0, 0, 0);
    }
    __syncthreads();  // reads done before next chunk's DMA
  }

  // Epilogue. C/D layout: col = lane&15, row = quad*4 + reg (m89/m91).
  int tcol[4], gcolv[4];
  float ncol[4];
#pragma unroll
  for (int sn = 0; sn < 4; sn++) {
    const int gc = colBase + wc * 64 + sn * 16 + l16;
    gcolv[sn] = gc;
    tcol[sn] = targets[gc];
    ncol[sn] = norms[gc];
  }
  float colmin[4] = {FINF, FINF, FINF, FINF};
#pragma unroll
  for (int sm = 0; sm < 2; sm++) {
#pragma unroll
    for (int r = 0; r < 4; r++) {
      const int rloc = wr * 32 + sm * 16 + quad * 4 + r;
      const int grow = rowBase + rloc;
      const int trow = targets[grow];
      const float nrow = norms[grow];
      float rowmin = FINF;
#pragma unroll
      for (int sn = 0; sn < 4; sn++) {
        const float sq = fmaxf(nrow + ncol[sn] - 2.0f * acc[sm][sn][r], 0.0f);
        if (tcol[sn] != trow) {
          rowmin = fminf(rowmin, sq);
          colmin[sn] = fminf(colmin[sn], sq);
        } else if (grow < gcolv[sn]) {  // same-class pair (i<j): emit once
          const unsigned int idx = atomicAdd(&s_pcnt, 1u);
          if (idx < PCAP) {
            s_pkey[idx] = ((unsigned int)grow << 12) | (unsigned int)gcolv[sn];
            s_psq[idx] = sq;
          } else {  // overflow fallback (rare)
            const unsigned int g = atomicAdd(&ctrl[0], 1u);
            pairs[g] = make_uint2(((unsigned int)grow << 12) | (unsigned int)gcolv[sn],
                                  __float_as_uint(sq));
          }
        }
      }
#pragma unroll
      for (int off = 1; off < 16; off <<= 1) rowmin = fminf(rowmin, __shfl_xor(rowmin, off));
      if (l16 == 0) s_rmin[wc][rloc] = rowmin;
    }
  }
#pragma unroll
  for (int sn = 0; sn < 4; sn++) {
    float cm = colmin[sn];
    cm = fminf(cm, __shfl_xor(cm, 16));
    cm = fminf(cm, __shfl_xor(cm, 32));
    if (quad == 0) s_cmin[wr][wc * 64 + sn * 16 + l16] = cm;
  }
  __syncthreads();
  if (tid < TROW) {
    const float m = fminf(s_rmin[0][tid], s_rmin[1][tid]);
    if (m < FINF) atomicMin(&an_sq_bits[rowBase + tid], __float_as_uint(m));
  } else if (tid < TROW + TCOL) {
    const int c = tid - TROW;
    const float m = fminf(s_cmin[0][c], s_cmin[1][c]);
    if (m < FINF) atomicMin(&an_sq_bits[colBase + c], __float_as_uint(m));
  }
  const unsigned int npair = min(s_pcnt, (unsigned int)PCAP);
  if (tid == 0) s_pbase = atomicAdd(&ctrl[0], npair);
  __syncthreads();
  for (unsigned int r = tid; r < npair; r += 256)
    pairs[s_pbase + r] = make_uint2(s_pkey[r], __float_as_uint(s_psq[r]));
}

// K3: flat pass over pair records + fused last-block finalize.
__global__ __launch_bounds__(256) void loss_kernel(const uint2* __restrict__ pairs,
                                                   const unsigned int* __restrict__ an_sq_bits,
                                                   float* __restrict__ accs,
                                                   unsigned int* __restrict__ ctrl,
                                                   float* __restrict__ out) {
  const int tid = threadIdx.x, wave = tid >> 6, lane = tid & 63;
  const unsigned int M = ctrl[0];
  __shared__ float s_sum[4];
  __shared__ unsigned int s_cnt[4], s_cor[4];
  __shared__ int s_last;
  float bsum = 0.f;
  unsigned int bcnt = 0, bcor = 0;
  for (unsigned int r = blockIdx.x * 256 + tid; r < M; r += LOSSB * 256) {
    const uint2 rec = pairs[r];
    const int a = (int)(rec.x >> 12);  // anchor (smaller original index)
    const float sq = __uint_as_float(rec.y);
    const float an = __uint_as_float(an_sq_bits[a]);
    if (sqrtf(sq) - sqrtf(an) + MARGIN > 0.0f) {
      bcnt++;
      bsum += fmaxf(sq - an + MARGIN, 0.0f);
      if (sq < an) bcor++;
    }
  }
#pragma unroll
  for (int off = 32; off > 0; off >>= 1) {
    bsum += __shfl_down(bsum, off);
    bcnt += __shfl_down(bcnt, off);
    bcor += __shfl_down(bcor, off);
  }
  if (lane == 0) { s_sum[wave] = bsum; s_cnt[wave] = bcnt; s_cor[wave] = bcor; }
  __syncthreads();
  if (tid == 0) {
    float* slot = accs + (size_t)(blockIdx.x & (C - 1)) * SLOTW;
    atomicAdd(&slot[0], s_sum[0] + s_sum[1] + s_sum[2] + s_sum[3]);
    atomicAdd((unsigned int*)&slot[1], s_cnt[0] + s_cnt[1] + s_cnt[2] + s_cnt[3]);
    atomicAdd((unsigned int*)&slot[2], s_cor[0] + s_cor[1] + s_cor[2] + s_cor[3]);
    __threadfence();  // release
    s_last = (atomicAdd(&ctrl[1], 1u) == (unsigned int)LOSSB - 1u);
  }
  __syncthreads();
  if (s_last) {
    __threadfence();  // acquire
    if (tid < C) {
      float sum = __uint_as_float(atomicAdd((unsigned int*)&accs[(size_t)tid * SLOTW + 0], 0u));
      unsigned int cnt = atomicAdd((unsigned int*)&accs[(size_t)tid * SLOTW + 1], 0u);
      unsigned int cor = atomicAdd((unsigned int*)&accs[(size_t)tid * SLOTW + 2], 0u);
#pragma unroll
      for (int off = 32; off > 0; off >>= 1) {
        sum += __shfl_down(sum, off);
        cnt += __shfl_down(cnt, off);
        cor += __shfl_down(cor, off);
      }
      if (tid == 0) {
        const float denom = (float)(cnt > 0u ? cnt : 1u);
        out[0] = sum / denom;
        out[1] = (float)cor / denom;
      }
    }
  }
}

extern "C" void kernel_launch(void* const* d_in, const int* in_sizes, int n_in,
                              void* d_out, int out_size, void* d_ws, size_t ws_size,
                              hipStream_t stream) {
  const float* E = (const float*)d_in[0];
  const int* targets = (const int*)d_in[1];
  float* out = (float*)d_out;
  char* ws = (char*)d_ws;
  size_t off = 0;
  unsigned short* Ebf = (unsigned short*)(ws + off); off += (size_t)N * D * 2;  // 4 MB
  float* norms = (float*)(ws + off); off += (size_t)N * 4;                      // 16 KB
  unsigned int* an_sq = (unsigned int*)(ws + off); off += (size_t)N * 4;        // 16 KB
  float* accs = (float*)(ws + off); off += (size_t)C * SLOTW * 4;               // 4 KB
  unsigned int* ctrl = (unsigned int*)(ws + off); off += 256;                   // cursor+done (zeroed by prep)
  uint2* pairs = (uint2*)(ws + off);                                            // pair records

  prep_kernel<<<dim3(N / 16), dim3(256), 0, stream>>>(E, Ebf, norms, an_sq, (unsigned int*)accs);
  gemm_min_kernel<<<dim3(NBLK), dim3(256), 0, stream>>>(Ebf, norms, targets, an_sq, pairs, ctrl);
  loss_kernel<<<dim3(LOSSB), dim3(256), 0, stream>>>(pairs, an_sq, accs, ctrl, out);
}